// Round 2
// baseline (25155.948 us; speedup 1.0000x reference)
//
#include <hip/hip_runtime.h>

typedef unsigned short u16;
typedef unsigned int u32;
typedef __attribute__((ext_vector_type(8))) short bf16x8;   // 8 bf16 = 4 VGPRs
typedef __attribute__((ext_vector_type(4))) float f32x4;
typedef __attribute__((ext_vector_type(4))) short s16x4;

#define LL 4
#define NN 32
#define SS 2048
#define VV 512
#define DD 512
#define LOOKAHEAD 4
#define NSLOT 8

#define FLAG_STRIDE 32                        // u32 per flag slot (128 B apart)
#define HBUF_BYTES (8 * 2 * 16 * DD * 2)      // 8 clusters x 2 bufs x 16 x 512 bf16
#define FLAG_BYTES (8 * 32 * FLAG_STRIDE * 4)
#define RING_OFF   (HBUF_BYTES + FLAG_BYTES)
#define RING_BYTES (8 * NSLOT * 16 * VV * 2)  // per-cluster x-slice ring, bf16

static __device__ __forceinline__ u16 f2bf(float f) {
    u32 x = __float_as_uint(f);
    x += 0x7fffu + ((x >> 16) & 1u);          // round-to-nearest-even
    return (u16)(x >> 16);
}

static __device__ __forceinline__ bf16x8 cvt8(const float* p) {
    f32x4 a = *(const f32x4*)p;
    f32x4 b = *(const f32x4*)(p + 4);
    bf16x8 r;
    r[0] = (short)f2bf(a[0]); r[1] = (short)f2bf(a[1]);
    r[2] = (short)f2bf(a[2]); r[3] = (short)f2bf(a[3]);
    r[4] = (short)f2bf(b[0]); r[5] = (short)f2bf(b[1]);
    r[6] = (short)f2bf(b[2]); r[7] = (short)f2bf(b[3]);
    return r;
}

// 256 blocks x 64 threads; one wave per block.
// cluster c = blockIdx%8 -> layer = c>>1, batch-half nb = c&1
// member  m = blockIdx/8 -> output features [16m, 16m+16)
__global__ __launch_bounds__(64, 1) void rnn_scan(
    const float* __restrict__ x,   // [N][S][V] f32
    const float* __restrict__ Wx,  // [L][D][V] f32
    const float* __restrict__ bx,  // [L][D]
    const float* __restrict__ Wh,  // [L][D][D]
    const float* __restrict__ bh,  // [L][D]
    float* __restrict__ out,       // [N][S][D] ++ [L][N][D]  f32
    u16* __restrict__ hbuf,        // [8][2][16][512] bf16
    u32* __restrict__ flags,       // [8][32] padded
    u16* __restrict__ ring)        // [8][NSLOT][16][512] bf16
{
    const int lane = threadIdx.x;
    const int c = blockIdx.x & 7;
    const int m = blockIdx.x >> 3;
    const int layer = c >> 1;
    const int nb = c & 1;
    const int e0 = m << 4;
    const int col = lane & 15;   // B/C column (= feature); also A row (= batch)
    const int quad = lane >> 4;

    // ---- weight-stationary B-fragments (f32 -> bf16) ----
    // lane holds B[k = quad*8+j + 32*ks][n = col] = W[e0+col][k]
    bf16x8 whf[16], wxf[16];
    {
        const float* wr = Wh + ((size_t)layer * DD + (e0 + col)) * DD + quad * 8;
#pragma unroll
        for (int ks = 0; ks < 16; ++ks) whf[ks] = cvt8(wr + 32 * ks);
        const float* xr = Wx + ((size_t)layer * DD + (e0 + col)) * VV + quad * 8;
#pragma unroll
        for (int ks = 0; ks < 16; ++ks) wxf[ks] = cvt8(xr + 32 * ks);
    }
    const float bias = bx[layer * DD + e0 + col] + bh[layer * DD + e0 + col];

    u16* hb = hbuf + (size_t)c * (2 * 16 * DD);
    u16* ringc = ring + (size_t)c * (NSLOT * 16 * VV);
    u32* fl = flags + (size_t)c * (32 * FLAG_STRIDE);
    u32* myflag = fl + m * FLAG_STRIDE;

    // cooperative f32->bf16 publish of x[t] slice: 4 elements per lane
    const int e = (m * 64 + lane) * 4;
    const int xrow_n = e >> 9;          // 0..15
    const int xcol_v = e & 511;
    const float* xsrc0 = x + ((size_t)(nb * 16 + xrow_n) * SS) * VV + xcol_v;
    u16* xdst0 = ringc + xrow_n * VV + xcol_v;

    auto publish_x = [&](int tconv) {
        if (tconv < SS) {
            f32x4 v = *(const f32x4*)(xsrc0 + (size_t)tconv * VV);
            s16x4 o;
            o[0] = (short)f2bf(v[0]); o[1] = (short)f2bf(v[1]);
            o[2] = (short)f2bf(v[2]); o[3] = (short)f2bf(v[3]);
            *(s16x4*)(xdst0 + (tconv & (NSLOT - 1)) * (16 * VV)) = o;
        }
    };

    auto waitall = [&](u32 tgt) {
        while (true) {
            u32 v = 0xffffffffu;
            if (lane < 32) v = atomicAdd(fl + lane * FLAG_STRIDE, 0u);  // coherent RMW read
            if (__all((int)(v >= tgt))) break;
            __builtin_amdgcn_s_sleep(2);
        }
    };

    // ---- prologue: publish x[0..LOOKAHEAD) ----
#pragma unroll
    for (int t0 = 0; t0 < LOOKAHEAD; ++t0) publish_x(t0);
    __threadfence();                       // release
    if (lane == 0) atomicExch(myflag, 1u); // prologue done
    waitall(1u);
    __threadfence();                       // acquire

    // A-frag pointers into ring/hbuf: lane holds A[row=col][k=quad*8+j+32ks]
    const u16* xrd_base = ringc + col * VV + quad * 8;
    bf16x8 xa0[16], xa1[16];
#pragma unroll
    for (int ks = 0; ks < 16; ++ks) xa0[ks] = *(const bf16x8*)(xrd_base + 32 * ks);

    auto step = [&](int t, bf16x8 (&cur)[16], bf16x8 (&nxt)[16]) {
        // publish x[t+LOOKAHEAD] for the cluster (safe: slot reread finished by flags>=t)
        publish_x(t + LOOKAHEAD);

        // prefetch next slot's A-frag (published in step t-3 or prologue)
        const u16* xn = xrd_base + ((t + 1) & (NSLOT - 1)) * (16 * VV);
#pragma unroll
        for (int ks = 0; ks < 16; ++ks) nxt[ks] = *(const bf16x8*)(xn + 32 * ks);

        // x-projection: independent of h, runs before the barrier
        f32x4 acc = {bias, bias, bias, bias};
#pragma unroll
        for (int ks = 0; ks < 16; ++ks)
            acc = __builtin_amdgcn_mfma_f32_16x16x32_bf16(cur[ks], wxf[ks], acc, 0, 0, 0);

        // wait: everyone finished step t-1 (flag = t+1) -> h[t-1] published
        waitall((u32)(t + 1));
        __threadfence();  // acquire

        // recurrent term: A = h[t-1], B = Wh slice from registers
        const u16* hrd = hb + ((t & 1) ^ 1) * (16 * DD) + col * DD + quad * 8;
        bf16x8 hf[16];
#pragma unroll
        for (int ks = 0; ks < 16; ++ks) hf[ks] = *(const bf16x8*)(hrd + 32 * ks);
#pragma unroll
        for (int ks = 0; ks < 16; ++ks)
            acc = __builtin_amdgcn_mfma_f32_16x16x32_bf16(hf[ks], whf[ks], acc, 0, 0, 0);

        // sigmoid + publish h[t] (bf16) + emit outputs (f32)
        u16* hwr = hb + (t & 1) * (16 * DD) + (quad * 4) * DD + e0 + col;
#pragma unroll
        for (int i = 0; i < 4; ++i) {
            const float s = 1.0f / (1.0f + __expf(-acc[i]));
            hwr[i * DD] = f2bf(s);
            const int n = nb * 16 + quad * 4 + i;
            if (layer == 3)  // ys: final_ans[n][t][d]
                out[((size_t)n * SS + t) * DD + e0 + col] = s;
            if (t == SS - 1) // h_final[l][n][d]
                out[(size_t)NN * SS * DD + ((size_t)layer * NN + n) * DD + e0 + col] = s;
        }
        __threadfence();  // release: h stores drain before flag
        if (lane == 0) atomicExch(myflag, (u32)(t + 2));
    };

    for (int t = 0; t < SS; t += 2) {
        step(t, xa0, xa1);
        step(t + 1, xa1, xa0);
    }
}

extern "C" void kernel_launch(void* const* d_in, const int* in_sizes, int n_in,
                              void* d_out, int out_size, void* d_ws, size_t ws_size,
                              hipStream_t stream) {
    const float* x  = (const float*)d_in[0];
    const float* Wx = (const float*)d_in[1];
    const float* bx = (const float*)d_in[2];
    const float* Wh = (const float*)d_in[3];
    const float* bh = (const float*)d_in[4];
    float* out = (float*)d_out;
    u16* hbuf = (u16*)d_ws;
    u32* flags = (u32*)((char*)d_ws + HBUF_BYTES);
    u16* ring = (u16*)((char*)d_ws + RING_OFF);

    // h0 = 0 and flags = 0 every call (ws is re-poisoned to 0xAA before timing)
    hipMemsetAsync(d_ws, 0, RING_OFF, stream);
    rnn_scan<<<dim3(256), dim3(64), 0, stream>>>(x, Wx, bx, Wh, bh, out, hbuf, flags, ring);
}

// Round 4
// 23226.160 us; speedup vs baseline: 1.0831x; 1.0831x over previous
//
#include <hip/hip_runtime.h>

typedef unsigned short u16;
typedef unsigned int u32;
typedef unsigned long long u64;
typedef __attribute__((ext_vector_type(8))) short bf16x8;   // 8 bf16 = 4 VGPRs
typedef __attribute__((ext_vector_type(4))) float f32x4;

#define LL 4
#define NN 32
#define SS 2048
#define VV 512
#define DD 512
#define CHUNK 16
#define NCHUNKS (SS / CHUNK)              // 128
#define PADR 520                           // h row stride (u16): 16B-aligned, odd*16B

#define NCONS 8
#define NBLOCKS 256
#define NPROD (NBLOCKS - NCONS)            // 248
#define FGROUPS 4                          // 128 feats per producer task
#define TASKS (NCHUNKS * NCONS * FGROUPS)  // 4096

// ws layout
#define PRODCNT_OFF 0                      // u32[8][NCHUNKS]
#define CONSDONE_OFF (NCONS * NCHUNKS * 4) // u32[8], 128B-padded
#define RING_OFF 8192
#define SLOT_BYTES ((size_t)NCONS * CHUNK * 8 * 64 * 32)   // 2 MB: [cl][t][w][lane][32B]

#define LDS_BYTES (131072 + 16 * PADR * 2) // 128K Wh-tile3 / B-stage  +  16.6K h

static __device__ __forceinline__ u16 f2bf(float f) {
    u32 x = __float_as_uint(f);
    x += 0x7fffu + ((x >> 16) & 1u);       // round-to-nearest-even
    return (u16)(x >> 16);
}
static __device__ __forceinline__ float bf2f(u32 h) {
    return __uint_as_float((h & 0xffffu) << 16);
}
static __device__ __forceinline__ bf16x8 cvt8(const float* p) {
    f32x4 a = *(const f32x4*)p;
    f32x4 b = *(const f32x4*)(p + 4);
    bf16x8 r;
    r[0] = (short)f2bf(a[0]); r[1] = (short)f2bf(a[1]);
    r[2] = (short)f2bf(a[2]); r[3] = (short)f2bf(a[3]);
    r[4] = (short)f2bf(b[0]); r[5] = (short)f2bf(b[1]);
    r[6] = (short)f2bf(b[2]); r[7] = (short)f2bf(b[3]);
    return r;
}

__global__ __launch_bounds__(512, 2) void rnn_fused(
    const float* __restrict__ x,   // [N][S][V]
    const float* __restrict__ Wx,  // [L][D][V]
    const float* __restrict__ bx,  // [L][D]
    const float* __restrict__ Wh,  // [L][D][D]
    const float* __restrict__ bh,  // [L][D]
    float* __restrict__ out,       // [N][S][D] ++ [L][N][D]
    char* __restrict__ ws, int nslots)
{
    extern __shared__ __align__(16) char lds[];
    const int tid = threadIdx.x;
    const int lane = tid & 63;
    const int w = tid >> 6;                // wave 0..7
    const int col = lane & 15, quad = lane >> 4;
    u32* prod_cnt = (u32*)(ws + PRODCNT_OFF);    // [cl][chunk]
    u32* cons_done = (u32*)(ws + CONSDONE_OFF);  // [cl*32]
    char* ring = ws + RING_OFF;

    if (blockIdx.x < NCONS) {
        // ================= consumer: the sequential scan =================
        const int cl = blockIdx.x;
        const int layer = cl >> 1, nb = cl & 1;
        u16* whlds = (u16*)lds;                   // [w][ks][lane][8 bf16] = 128 KB (tile 3)
        u16* hb = (u16*)(lds + 131072);           // [16][PADR]

        // Wh: tiles 0..2 -> registers (192 VGPR), tile 3 -> LDS
        bf16x8 whf[48];
#pragma unroll
        for (int tl = 0; tl < 3; ++tl)
#pragma unroll
            for (int ks = 0; ks < 16; ++ks)
                whf[tl * 16 + ks] =
                    cvt8(Wh + ((size_t)layer * DD + (w * 64 + tl * 16 + col)) * DD + 32 * ks + quad * 8);
#pragma unroll
        for (int ks = 0; ks < 16; ++ks) {
            bf16x8 f = cvt8(Wh + ((size_t)layer * DD + (w * 64 + 48 + col)) * DD + 32 * ks + quad * 8);
            *(bf16x8*)(whlds + ((size_t)(w * 16 + ks) * 64 + lane) * 8) = f;
        }
        for (int i = tid; i < 16 * PADR; i += 512) hb[i] = 0;   // h[-1] = 0
        __syncthreads();

        auto xp_addr = [&](int t) -> const u64* {
            const int slot = (t >> 4) % nslots;
            return (const u64*)(ring +
                ((((size_t)(slot * NCONS + cl) * CHUNK + (t & 15)) * 8 + w) * 64 + lane) * 32);
        };
        // wait chunk 0, preload xp[0]
        while (__hip_atomic_load(&prod_cnt[cl * NCHUNKS + 0], __ATOMIC_ACQUIRE,
                                 __HIP_MEMORY_SCOPE_AGENT) < FGROUPS)
            __builtin_amdgcn_s_sleep(8);
        u64 xpbuf[2][4];
        {
            const u64* p = xp_addr(0);
#pragma unroll
            for (int j = 0; j < 4; ++j)
                xpbuf[0][j] = __hip_atomic_load(p + j, __ATOMIC_RELAXED, __HIP_MEMORY_SCOPE_AGENT);
        }

        const u16* hrd = hb + col * PADR + quad * 8;
        u16* hwr = hb + (quad * 4) * PADR + w * 64 + col;
        float* outp = out + ((size_t)(nb * 16 + quad * 4) * SS) * DD + w * 64 + col;   // layer 3
        float* out2 = out + (size_t)NN * SS * DD
                    + ((size_t)layer * NN + nb * 16 + quad * 4) * DD + w * 64 + col;

        for (int t = 0; t < SS; ++t) {
            const int cur = t & 1;
            // acc init from xp[t] (bias already folded in by producer)
            f32x4 acc[4];
#pragma unroll
            for (int tl = 0; tl < 4; ++tl) {
                const u64 v = xpbuf[cur][tl];
                acc[tl][0] = bf2f((u32)v);
                acc[tl][1] = bf2f((u32)(v >> 16));
                acc[tl][2] = bf2f((u32)(v >> 32));
                acc[tl][3] = bf2f((u32)(v >> 48));
            }
            // chunk boundary: ack consumed chunk BEFORE polling the next (nslots=1-safe)
            if ((t & 15) == 15) {
                __syncthreads();
                if (tid == 0)
                    __hip_atomic_store(&cons_done[cl * 32], (u32)((t >> 4) + 1),
                                       __ATOMIC_RELEASE, __HIP_MEMORY_SCOPE_AGENT);
            }
            // prefetch xp[t+1]
            if (t + 1 < SS) {
                if (((t + 1) & 15) == 0) {
                    const int nc = (t + 1) >> 4;
                    while (__hip_atomic_load(&prod_cnt[cl * NCHUNKS + nc], __ATOMIC_ACQUIRE,
                                             __HIP_MEMORY_SCOPE_AGENT) < FGROUPS)
                        __builtin_amdgcn_s_sleep(8);
                }
                const u64* p = xp_addr(t + 1);
#pragma unroll
                for (int j = 0; j < 4; ++j)
                    xpbuf[cur ^ 1][j] =
                        __hip_atomic_load(p + j, __ATOMIC_RELAXED, __HIP_MEMORY_SCOPE_AGENT);
            }
            // recurrent GEMM: A = h[t-1] (LDS), B = Wh (regs + LDS tile 3)
#pragma unroll
            for (int ks = 0; ks < 16; ++ks) {
                bf16x8 a = *(const bf16x8*)(hrd + 32 * ks);
                acc[0] = __builtin_amdgcn_mfma_f32_16x16x32_bf16(a, whf[ks], acc[0], 0, 0, 0);
                acc[1] = __builtin_amdgcn_mfma_f32_16x16x32_bf16(a, whf[16 + ks], acc[1], 0, 0, 0);
                acc[2] = __builtin_amdgcn_mfma_f32_16x16x32_bf16(a, whf[32 + ks], acc[2], 0, 0, 0);
                bf16x8 b3 = *(const bf16x8*)(whlds + ((size_t)(w * 16 + ks) * 64 + lane) * 8);
                acc[3] = __builtin_amdgcn_mfma_f32_16x16x32_bf16(a, b3, acc[3], 0, 0, 0);
            }
            __syncthreads();   // barrier 1: all h[t-1] reads done
            // sigmoid + h[t] publish + outputs
#pragma unroll
            for (int tl = 0; tl < 4; ++tl)
#pragma unroll
                for (int i = 0; i < 4; ++i) {
                    const float s = 1.0f / (1.0f + __expf(-acc[tl][i]));
                    hwr[i * PADR + tl * 16] = f2bf(s);
                    if (layer == 3) outp[((size_t)i * SS + t) * DD + tl * 16] = s;
                    if (t == SS - 1) out2[(size_t)i * DD + tl * 16] = s;
                }
            __syncthreads();   // barrier 2: h[t] visible
        }
    } else {
        // ================= producers: xp = Wx x + (bx+bh), chunked =================
        u16* blds = (u16*)lds;   // Wx B-frags: [ct 8][ks 16][lane 64][8 bf16] = 128 KB
        for (int task = blockIdx.x - NCONS; task < TASKS; task += NPROD) {
            const int chunk = task >> 5;
            const int rem = task & 31;
            const int cl = rem >> 2, fg = rem & 3;
            const int layer = cl >> 1, nb = cl & 1;
            const int slot = chunk % nslots;
            // bounded-buffer gate: slot free when consumer finished chunk - nslots
            if (chunk >= nslots && tid == 0) {
                while ((int)__hip_atomic_load(&cons_done[cl * 32], __ATOMIC_ACQUIRE,
                                              __HIP_MEMORY_SCOPE_AGENT) < chunk - nslots + 1)
                    __builtin_amdgcn_s_sleep(16);
            }
            __syncthreads();   // gate known + previous task's LDS reads done
            // stage B = Wx[layer][fg*128 ..+128][512] as bf16 fragments in LDS
            for (int r = 0; r < 16; ++r) {
                const int li = (r * 512 + tid) * 8;
                const int row = li >> 9, k0 = li & 511;
                bf16x8 v = cvt8(Wx + ((size_t)layer * DD + fg * 128 + row) * VV + k0);
                const int ct = row >> 4, fcol = row & 15, ks = k0 >> 5, q = (k0 >> 3) & 3;
                *(bf16x8*)(blds + ((size_t)((ct * 16 + ks) * 64 + q * 16 + fcol)) * 8) = v;
            }
            float bias[8];
#pragma unroll
            for (int ct = 0; ct < 8; ++ct) {
                const int f = layer * DD + fg * 128 + ct * 16 + col;
                bias[ct] = bx[f] + bh[f];
            }
            __syncthreads();
            // compute: wave w -> t_local {2w, 2w+1}; rows = 16 batches
            const int t0 = chunk * CHUNK;
            f32x4 acc[2][8];
#pragma unroll
            for (int rt = 0; rt < 2; ++rt)
#pragma unroll
                for (int ct = 0; ct < 8; ++ct)
                    acc[rt][ct] = f32x4{bias[ct], bias[ct], bias[ct], bias[ct]};
            const float* xr0 = x + ((size_t)(nb * 16 + col) * SS + (t0 + 2 * w)) * VV + quad * 8;
#pragma unroll
            for (int ks = 0; ks < 16; ++ks) {
                bf16x8 a0 = cvt8(xr0 + 32 * ks);
                bf16x8 a1 = cvt8(xr0 + VV + 32 * ks);
#pragma unroll
                for (int ct = 0; ct < 8; ++ct) {
                    bf16x8 b = *(const bf16x8*)(blds + ((size_t)((ct * 16 + ks) * 64 + lane)) * 8);
                    acc[0][ct] = __builtin_amdgcn_mfma_f32_16x16x32_bf16(a0, b, acc[0][ct], 0, 0, 0);
                    acc[1][ct] = __builtin_amdgcn_mfma_f32_16x16x32_bf16(a1, b, acc[1][ct], 0, 0, 0);
                }
            }
            // store in consumer C-frag order: bf16x4 packed u64, agent-scope (L2-bypass)
#pragma unroll
            for (int rt = 0; rt < 2; ++rt) {
                char* base = ring + ((size_t)(slot * NCONS + cl) * CHUNK + (2 * w + rt)) * (8 * 64 * 32);
#pragma unroll
                for (int ct = 0; ct < 8; ++ct) {
                    const int gct = fg * 8 + ct, wc = gct >> 2, tl = gct & 3;
                    const f32x4 a = acc[rt][ct];
                    u64 v = (u64)f2bf(a[0]) | ((u64)f2bf(a[1]) << 16)
                          | ((u64)f2bf(a[2]) << 32) | ((u64)f2bf(a[3]) << 48);
                    __hip_atomic_store((u64*)(base + ((size_t)wc * 64 + lane) * 32 + tl * 8), v,
                                       __ATOMIC_RELAXED, __HIP_MEMORY_SCOPE_AGENT);
                }
            }
            __syncthreads();   // drains all waves' stores (vmcnt0 before s_barrier)
            if (tid == 0)
                __hip_atomic_fetch_add(&prod_cnt[cl * NCHUNKS + chunk], 1u,
                                       __ATOMIC_RELEASE, __HIP_MEMORY_SCOPE_AGENT);
        }
    }
}

extern "C" void kernel_launch(void* const* d_in, const int* in_sizes, int n_in,
                              void* d_out, int out_size, void* d_ws, size_t ws_size,
                              hipStream_t stream) {
    const float* x  = (const float*)d_in[0];
    const float* Wx = (const float*)d_in[1];
    const float* bx = (const float*)d_in[2];
    const float* Wh = (const float*)d_in[3];
    const float* bh = (const float*)d_in[4];
    float* out = (float*)d_out;
    char* ws = (char*)d_ws;

    int nslots = 1;
    if (ws_size > RING_OFF + SLOT_BYTES) {
        size_t n = (ws_size - RING_OFF) / SLOT_BYTES;
        nslots = (int)(n > 8 ? 8 : n);
    }
    hipFuncSetAttribute((const void*)rnn_fused,
                        hipFuncAttributeMaxDynamicSharedMemorySize, LDS_BYTES);
    hipMemsetAsync(ws, 0, RING_OFF, stream);   // zero flags (ws is re-poisoned each call)
    rnn_fused<<<dim3(NBLOCKS), dim3(512), LDS_BYTES, stream>>>(x, Wx, bx, Wh, bh, out, ws, nslots);
}